// Round 1
// baseline (1143.359 us; speedup 1.0000x reference)
//
#include <hip/hip_runtime.h>
#include <hip/hip_bf16.h>
#include <math.h>

#define N_NODES 100000
#define N_EDGES 3200000
#define HID 32
#define K_TOP 30
#define N_GRAPHS 2000
#define NPG 50
#define TLD 97
#define DENSE 352

// ---------------- CSR build ----------------
__global__ void k_count_deg(const int* __restrict__ dst, int* __restrict__ deg, int E) {
    int e = blockIdx.x * blockDim.x + threadIdx.x;
    if (e < E) atomicAdd(&deg[dst[e]], 1);
}

// per-block exclusive scan of deg -> row_ptr, block sums -> partials
__global__ void k_scanA(const int* __restrict__ deg, int* __restrict__ row_ptr,
                        int* __restrict__ partials, int N) {
    __shared__ int s[256];
    int tid = threadIdx.x;
    int n = blockIdx.x * 256 + tid;
    int v = (n < N) ? deg[n] : 0;
    s[tid] = v;
    __syncthreads();
    for (int off = 1; off < 256; off <<= 1) {
        int t = (tid >= off) ? s[tid - off] : 0;
        __syncthreads();
        s[tid] += t;
        __syncthreads();
    }
    if (n < N) row_ptr[n] = s[tid] - v;   // exclusive within block
    if (tid == 255) partials[blockIdx.x] = s[tid];
}

__global__ void k_scanB(int* __restrict__ partials, int nb) {
    __shared__ int s[512];
    int tid = threadIdx.x;
    int v = (tid < nb) ? partials[tid] : 0;
    s[tid] = v;
    __syncthreads();
    for (int off = 1; off < 512; off <<= 1) {
        int t = (tid >= off) ? s[tid - off] : 0;
        __syncthreads();
        s[tid] += t;
        __syncthreads();
    }
    if (tid < nb) partials[tid] = s[tid] - v;  // exclusive across blocks
}

__global__ void k_scanC(int* __restrict__ row_ptr, const int* __restrict__ partials,
                        const int* __restrict__ deg, int* __restrict__ cursor,
                        float* __restrict__ dinv, int N) {
    int n = blockIdx.x * 256 + threadIdx.x;
    if (n < N) {
        int r = row_ptr[n] + partials[blockIdx.x];
        row_ptr[n] = r;
        cursor[n]  = r;
        dinv[n] = rsqrtf((float)(deg[n] + 1));  // +1 self loop
    }
    if (n == 0) row_ptr[N] = N_EDGES;
}

__global__ void k_fill(const int* __restrict__ src, const int* __restrict__ dst,
                       int* __restrict__ cursor, int* __restrict__ col, int E) {
    int e = blockIdx.x * blockDim.x + threadIdx.x;
    if (e >= E) return;
    int pos = atomicAdd(&cursor[dst[e]], 1);
    col[pos] = src[e];
}

// ---------------- GCN layers ----------------
__global__ void k_embed(const int* __restrict__ z, const float* __restrict__ zt,
                        float* __restrict__ h) {
    int i = blockIdx.x * blockDim.x + threadIdx.x;
    if (i < N_NODES * HID) {
        int n = i >> 5, f = i & 31;
        h[i] = zt[z[n] * HID + f];
    }
}

// hs[n][o] = (h_in[n] @ W)[o] * dinv[n]
__global__ void k_lin32(const float* __restrict__ hin, const float* __restrict__ W,
                        const float* __restrict__ dinv, float* __restrict__ hout) {
    __shared__ float Ws[32 * 32];
    int tid = threadIdx.x;
    for (int i = tid; i < 1024; i += 256) Ws[i] = W[i];
    __syncthreads();
    int gi = blockIdx.x * 256 + tid;
    if (gi >= N_NODES * 32) return;
    int n = gi >> 5, o = gi & 31;
    const float* row = hin + n * 32;
    float acc = 0.f;
#pragma unroll
    for (int i = 0; i < 32; ++i) acc += row[i] * Ws[i * 32 + o];
    hout[gi] = acc * dinv[n];
}

// out[n][f] = tanh(dinv[n]*(hs[n][f] + sum_src hs[src][f]) + b[f]) -> hA and xcat col block
__global__ void k_prop32(const float* __restrict__ hs, const int* __restrict__ row_ptr,
                         const int* __restrict__ col, const float* __restrict__ dinv,
                         const float* __restrict__ b, float* __restrict__ hout,
                         float* __restrict__ xcat, int coloff) {
    int gi = blockIdx.x * blockDim.x + threadIdx.x;
    if (gi >= N_NODES * 32) return;
    int n = gi >> 5, f = gi & 31;
    int beg = row_ptr[n], end = row_ptr[n + 1];
    float acc = hs[n * 32 + f];
    for (int e = beg; e < end; ++e)
        acc += hs[col[e] * 32 + f];
    float v = tanhf(acc * dinv[n] + b[f]);
    hout[n * 32 + f] = v;
    xcat[n * 97 + coloff + f] = v;
}

// hs4[n] = (h_in[n] . W3) * dinv[n]   (32-lane group reduce)
__global__ void k_lin4(const float* __restrict__ hin, const float* __restrict__ W,
                       const float* __restrict__ dinv, float* __restrict__ h4) {
    int gi = blockIdx.x * blockDim.x + threadIdx.x;
    int n = gi >> 5, f = gi & 31;
    if (n >= N_NODES) return;
    float v = hin[n * 32 + f] * W[f];
    for (int off = 16; off >= 1; off >>= 1) v += __shfl_xor(v, off);
    if (f == 0) h4[n] = v * dinv[n];
}

__global__ void k_prop1(const float* __restrict__ hs4, const int* __restrict__ row_ptr,
                        const int* __restrict__ col, const float* __restrict__ dinv,
                        const float* __restrict__ b3, float* __restrict__ xcat) {
    int n = blockIdx.x * blockDim.x + threadIdx.x;
    if (n >= N_NODES) return;
    int beg = row_ptr[n], end = row_ptr[n + 1];
    float acc = hs4[n];
    for (int e = beg; e < end; ++e) acc += hs4[col[e]];
    xcat[n * 97 + 96] = tanhf(acc * dinv[n] + b3[0]);
}

// ---------------- fused sort-pool + CNN + MLP head ----------------
__global__ __launch_bounds__(128) void k_head(
    const float* __restrict__ xcat,
    const float* __restrict__ w1, const float* __restrict__ b1,
    const float* __restrict__ w2, const float* __restrict__ b2,
    const float* __restrict__ l1w, const float* __restrict__ l1b,
    const float* __restrict__ l2w, const float* __restrict__ l2b,
    float* __restrict__ out) {
    __shared__ float xk[K_TOP][97];
    __shared__ float w1s[16 * 97];
    __shared__ float w2s[32 * 80];
    __shared__ float y1[16][K_TOP];
    __shared__ float y1p[16][15];
    __shared__ float y2[DENSE];
    __shared__ float z1[128];
    __shared__ int   sel[K_TOP];
    __shared__ float red[2];

    int g = blockIdx.x;
    int tid = threadIdx.x;
    int base = g * NPG;

    for (int i = tid; i < 16 * 97; i += 128) w1s[i] = w1[i];
    for (int i = tid; i < 32 * 80; i += 128) w2s[i] = w2[i];

    // wave 0: stable descending bitonic sort of 50 keys (padded to 64)
    if (tid < 64) {
        float v; int idx;
        if (tid < NPG) { v = xcat[(base + tid) * 97 + 96]; idx = tid; }
        else           { v = -INFINITY;                    idx = 64 + tid; }
        for (int k = 2; k <= 64; k <<= 1) {
            for (int j = k >> 1; j > 0; j >>= 1) {
                float ov = __shfl_xor(v, j);
                int   oi = __shfl_xor(idx, j);
                bool lower = (tid & j) == 0;
                bool dirA  = (tid & k) == 0;
                bool mineFirst = (v > ov) || (v == ov && idx < oi);
                bool keep = lower ? (mineFirst == dirA) : (mineFirst != dirA);
                if (!keep) { v = ov; idx = oi; }
            }
        }
        if (tid < K_TOP) sel[tid] = idx;
    }
    __syncthreads();

    // stage top-30 feature rows
    for (int i = tid; i < K_TOP * 97; i += 128) {
        int j = i / 97, d = i - j * 97;
        xk[j][d] = xcat[(base + sel[j]) * 97 + d];
    }
    __syncthreads();

    // conv1 (97 -> 16 per kept node) + relu
    for (int i = tid; i < 16 * K_TOP; i += 128) {
        int c = i / K_TOP, j = i - c * K_TOP;
        float acc = b1[c];
#pragma unroll
        for (int d = 0; d < 97; ++d) acc += xk[j][d] * w1s[c * 97 + d];
        y1[c][j] = fmaxf(acc, 0.f);
    }
    __syncthreads();

    // maxpool(2,2)
    for (int i = tid; i < 16 * 15; i += 128) {
        int c = i / 15, p = i - c * 15;
        y1p[c][p] = fmaxf(y1[c][2 * p], y1[c][2 * p + 1]);
    }
    __syncthreads();

    // conv2 (16->32, k=5) + relu
    for (int i = tid; i < 32 * 11; i += 128) {
        int o = i / 11, p = i - o * 11;
        float acc = b2[o];
#pragma unroll
        for (int ci = 0; ci < 16; ++ci)
#pragma unroll
            for (int t = 0; t < 5; ++t)
                acc += y1p[ci][p + t] * w2s[o * 80 + ci * 5 + t];
        y2[o * 11 + p] = fmaxf(acc, 0.f);
    }
    __syncthreads();

    // lin1 (352 -> 128) + relu
    {
        float acc = l1b[tid];
        for (int r = 0; r < DENSE; ++r) acc += y2[r] * l1w[r * 128 + tid];
        z1[tid] = fmaxf(acc, 0.f);
    }
    __syncthreads();

    // lin2 (128 -> 1)
    float p = z1[tid] * l2w[tid];
    for (int off = 32; off >= 1; off >>= 1) p += __shfl_xor(p, off);
    if ((tid & 63) == 0) red[tid >> 6] = p;
    __syncthreads();
    if (tid == 0) out[g] = red[0] + red[1] + l2b[0];
}

extern "C" void kernel_launch(void* const* d_in, const int* in_sizes, int n_in,
                              void* d_out, int out_size, void* d_ws, size_t ws_size,
                              hipStream_t stream) {
    const int*   z   = (const int*)d_in[0];
    const int*   ei  = (const int*)d_in[1];
    const float* zt  = (const float*)d_in[3];
    const float* W0  = (const float*)d_in[4];  const float* b0  = (const float*)d_in[5];
    const float* W1  = (const float*)d_in[6];  const float* b1g = (const float*)d_in[7];
    const float* W2  = (const float*)d_in[8];  const float* b2g = (const float*)d_in[9];
    const float* W3  = (const float*)d_in[10]; const float* b3  = (const float*)d_in[11];
    const float* c1w = (const float*)d_in[12]; const float* c1b = (const float*)d_in[13];
    const float* c2w = (const float*)d_in[14]; const float* c2b = (const float*)d_in[15];
    const float* l1w = (const float*)d_in[16]; const float* l1b = (const float*)d_in[17];
    const float* l2w = (const float*)d_in[18]; const float* l2b = (const float*)d_in[19];
    float* out = (float*)d_out;

    char* ws = (char*)d_ws;
    size_t off = 0;
    auto alloc = [&](size_t bytes) {
        void* p = ws + off;
        off += (bytes + 255) & ~(size_t)255;
        return p;
    };
    int*   deg      = (int*)alloc((size_t)N_NODES * 4);
    int*   row_ptr  = (int*)alloc((size_t)(N_NODES + 1) * 4);
    int*   cursor   = (int*)alloc((size_t)N_NODES * 4);
    int*   partials = (int*)alloc(512 * 4);
    float* dinv     = (float*)alloc((size_t)N_NODES * 4);
    int*   col      = (int*)alloc((size_t)N_EDGES * 4);
    float* hA       = (float*)alloc((size_t)N_NODES * 32 * 4);
    float* hB       = (float*)alloc((size_t)N_NODES * 32 * 4);
    float* h4       = (float*)alloc((size_t)N_NODES * 4);
    float* xcat     = (float*)alloc((size_t)N_NODES * 97 * 4);

    const int* srcp = ei;
    const int* dstp = ei + N_EDGES;

    hipMemsetAsync(deg, 0, (size_t)N_NODES * 4, stream);

    int eb = (N_EDGES + 255) / 256;
    int nb = (N_NODES + 255) / 256;   // 391 <= 512
    int nf = (N_NODES * 32 + 255) / 256;

    k_count_deg<<<eb, 256, 0, stream>>>(dstp, deg, N_EDGES);
    k_scanA<<<nb, 256, 0, stream>>>(deg, row_ptr, partials, N_NODES);
    k_scanB<<<1, 512, 0, stream>>>(partials, nb);
    k_scanC<<<nb, 256, 0, stream>>>(row_ptr, partials, deg, cursor, dinv, N_NODES);
    k_fill<<<eb, 256, 0, stream>>>(srcp, dstp, cursor, col, N_EDGES);

    k_embed<<<nf, 256, 0, stream>>>(z, zt, hA);

    const float* Ws[3] = {W0, W1, W2};
    const float* bs[3] = {b0, b1g, b2g};
    for (int l = 0; l < 3; ++l) {
        k_lin32<<<nf, 256, 0, stream>>>(hA, Ws[l], dinv, hB);
        k_prop32<<<nf, 256, 0, stream>>>(hB, row_ptr, col, dinv, bs[l], hA, xcat, l * 32);
    }
    k_lin4<<<nf, 256, 0, stream>>>(hA, W3, dinv, h4);
    k_prop1<<<nb, 256, 0, stream>>>(h4, row_ptr, col, dinv, b3, xcat);

    k_head<<<N_GRAPHS, 128, 0, stream>>>(xcat, c1w, c1b, c2w, c2b,
                                         l1w, l1b, l2w, l2b, out);
}

// Round 8
// 908.337 us; speedup vs baseline: 1.2587x; 1.2587x over previous
//
#include <hip/hip_runtime.h>
#include <hip/hip_bf16.h>
#include <math.h>

#define N_NODES 100000
#define N_EDGES 3200000
#define HID 32
#define K_TOP 30
#define N_GRAPHS 2000
#define NPG 50
#define TLD 97
#define DENSE 352
#define NSHARD 8
#define NPS 12500   // nodes per shard

// ---------------- CSR build (XCD-sharded) ----------------
// block b serves shard b%8; shard owns node range [s*NPS,(s+1)*NPS).
// Writes/atomics become XCD-local -> L2-resident, single eviction.
// dst/src streams are nontemporal: 8x re-read, must not displace the
// shard's L2-resident deg/cursor/col slices.
__global__ void k_count_deg(const int* __restrict__ dst, int* __restrict__ deg, int E) {
    int shard = blockIdx.x & 7;
    int r = blockIdx.x >> 3;
    int T = (gridDim.x >> 3) * blockDim.x;
    int lo = shard * NPS, hi = lo + NPS;
    for (int e = r * blockDim.x + threadIdx.x; e < E; e += T) {
        int d = __builtin_nontemporal_load(&dst[e]);
        if (d >= lo && d < hi) atomicAdd(&deg[d], 1);
    }
}

__global__ void k_scanA(const int* __restrict__ deg, int* __restrict__ row_ptr,
                        int* __restrict__ partials, int N) {
    __shared__ int s[256];
    int tid = threadIdx.x;
    int n = blockIdx.x * 256 + tid;
    int v = (n < N) ? deg[n] : 0;
    s[tid] = v;
    __syncthreads();
    for (int off = 1; off < 256; off <<= 1) {
        int t = (tid >= off) ? s[tid - off] : 0;
        __syncthreads();
        s[tid] += t;
        __syncthreads();
    }
    if (n < N) row_ptr[n] = s[tid] - v;
    if (tid == 255) partials[blockIdx.x] = s[tid];
}

__global__ void k_scanB(int* __restrict__ partials, int nb) {
    __shared__ int s[512];
    int tid = threadIdx.x;
    int v = (tid < nb) ? partials[tid] : 0;
    s[tid] = v;
    __syncthreads();
    for (int off = 1; off < 512; off <<= 1) {
        int t = (tid >= off) ? s[tid - off] : 0;
        __syncthreads();
        s[tid] += t;
        __syncthreads();
    }
    if (tid < nb) partials[tid] = s[tid] - v;
}

__global__ void k_scanC(int* __restrict__ row_ptr, const int* __restrict__ partials,
                        const int* __restrict__ deg, int* __restrict__ cursor,
                        float* __restrict__ dinv, int N) {
    int n = blockIdx.x * 256 + threadIdx.x;
    if (n < N) {
        int r = row_ptr[n] + partials[blockIdx.x];
        row_ptr[n] = r;
        cursor[n]  = r;
        dinv[n] = rsqrtf((float)(deg[n] + 1));
    }
    if (n == 0) row_ptr[N] = N_EDGES;
}

__global__ void k_fill(const int* __restrict__ src, const int* __restrict__ dst,
                       int* __restrict__ cursor, int* __restrict__ col, int E) {
    int shard = blockIdx.x & 7;
    int r = blockIdx.x >> 3;
    int T = (gridDim.x >> 3) * blockDim.x;
    int lo = shard * NPS, hi = lo + NPS;
    for (int e = r * blockDim.x + threadIdx.x; e < E; e += T) {
        int d = __builtin_nontemporal_load(&dst[e]);
        if (d >= lo && d < hi) {
            int pos = atomicAdd(&cursor[d], 1);
            col[pos] = __builtin_nontemporal_load(&src[e]);
        }
    }
}

// ---------------- fused GCN layers ----------------
// hs0[n][o] = (zt[z[n]] @ W0)[o] * dinv[n]
__global__ void k_embed_lin0(const int* __restrict__ z, const float* __restrict__ zt,
                             const float* __restrict__ W, const float* __restrict__ dinv,
                             float* __restrict__ hs) {
    __shared__ float Ws[32 * 32];
    int tid = threadIdx.x;
    for (int i = tid; i < 1024; i += 256) Ws[i] = W[i];
    __syncthreads();
    int gi = blockIdx.x * 256 + tid;
    if (gi >= N_NODES * 32) return;
    int n = gi >> 5, f = gi & 31;
    float v = zt[z[n] * 32 + f];
    float acc = 0.f;
#pragma unroll
    for (int f2 = 0; f2 < 32; ++f2)
        acc += __shfl(v, f2, 32) * Ws[f2 * 32 + f];
    hs[gi] = acc * dinv[n];
}

// one GCN layer: gather-normalize-tanh, write xcat column block, then fused
// next-layer linear: hs_out = (v @ Wnext) * dinv
// Gather: full 32-edge chunks take an unrolled path (same FP order) so the
// compiler can batch the 32 independent row-loads ahead of the add chain.
__global__ void k_layer(const float* __restrict__ hs, const int* __restrict__ row_ptr,
                        const int* __restrict__ col, const float* __restrict__ dinv,
                        const float* __restrict__ b, const float* __restrict__ Wnext,
                        float* __restrict__ xcat, int coloff,
                        float* __restrict__ hs_out) {
    __shared__ float Ws[32 * 32];
    int tid = threadIdx.x;
    for (int i = tid; i < 1024; i += 256) Ws[i] = Wnext[i];
    __syncthreads();
    int gi = blockIdx.x * 256 + tid;
    if (gi >= N_NODES * 32) return;
    int n = gi >> 5, f = gi & 31;
    int beg = row_ptr[n], end = row_ptr[n + 1];
    float acc = hs[n * 32 + f];
    int nfull = (end - beg) & ~31;
    int base = beg;
    for (; base < beg + nfull; base += 32) {
        int c = col[base + f];
#pragma unroll
        for (int i = 0; i < 32; ++i) {
            int ci = __shfl(c, i, 32);
            acc += hs[ci * 32 + f];
        }
    }
    int m = end - base;
    if (m > 0) {
        int c = (f < m) ? col[base + f] : 0;
        for (int i = 0; i < m; ++i) {
            int ci = __shfl(c, i, 32);
            acc += hs[ci * 32 + f];
        }
    }
    float v = tanhf(acc * dinv[n] + b[f]);
    xcat[n * 97 + coloff + f] = v;
    float a2 = 0.f;
#pragma unroll
    for (int f2 = 0; f2 < 32; ++f2)
        a2 += __shfl(v, f2, 32) * Ws[f2 * 32 + f];
    hs_out[n * 32 + f] = a2 * dinv[n];
}

// last 32-wide layer: same gather, but fused (v . W3) * dinv scalar reduce
__global__ void k_layer_last(const float* __restrict__ hs, const int* __restrict__ row_ptr,
                             const int* __restrict__ col, const float* __restrict__ dinv,
                             const float* __restrict__ b, const float* __restrict__ W3,
                             float* __restrict__ xcat, int coloff,
                             float* __restrict__ h4) {
    int gi = blockIdx.x * 256 + threadIdx.x;
    if (gi >= N_NODES * 32) return;
    int n = gi >> 5, f = gi & 31;
    int beg = row_ptr[n], end = row_ptr[n + 1];
    float acc = hs[n * 32 + f];
    int nfull = (end - beg) & ~31;
    int base = beg;
    for (; base < beg + nfull; base += 32) {
        int c = col[base + f];
#pragma unroll
        for (int i = 0; i < 32; ++i) {
            int ci = __shfl(c, i, 32);
            acc += hs[ci * 32 + f];
        }
    }
    int m = end - base;
    if (m > 0) {
        int c = (f < m) ? col[base + f] : 0;
        for (int i = 0; i < m; ++i) {
            int ci = __shfl(c, i, 32);
            acc += hs[ci * 32 + f];
        }
    }
    float v = tanhf(acc * dinv[n] + b[f]);
    xcat[n * 97 + coloff + f] = v;
    float p = v * W3[f];
#pragma unroll
    for (int off = 16; off >= 1; off >>= 1) p += __shfl_xor(p, off);
    if (f == 0) h4[n] = p * dinv[n];
}

__global__ void k_prop1(const float* __restrict__ hs4, const int* __restrict__ row_ptr,
                        const int* __restrict__ col, const float* __restrict__ dinv,
                        const float* __restrict__ b3, float* __restrict__ xcat) {
    int n = blockIdx.x * blockDim.x + threadIdx.x;
    if (n >= N_NODES) return;
    int beg = row_ptr[n], end = row_ptr[n + 1];
    float acc = hs4[n];
    for (int e = beg; e < end; ++e) acc += hs4[col[e]];
    xcat[n * 97 + 96] = tanhf(acc * dinv[n] + b3[0]);
}

// ---------------- fused sort-pool + CNN + MLP head ----------------
__global__ __launch_bounds__(128) void k_head(
    const float* __restrict__ xcat,
    const float* __restrict__ w1, const float* __restrict__ b1,
    const float* __restrict__ w2, const float* __restrict__ b2,
    const float* __restrict__ l1w, const float* __restrict__ l1b,
    const float* __restrict__ l2w, const float* __restrict__ l2b,
    float* __restrict__ out) {
    __shared__ float xk[K_TOP][97];
    __shared__ float w1s[16 * 97];
    __shared__ float w2s[32 * 80];
    __shared__ float y1[16][K_TOP];
    __shared__ float y1p[16][15];
    __shared__ float y2[DENSE];
    __shared__ float z1[128];
    __shared__ int   sel[K_TOP];
    __shared__ float red[2];

    int g = blockIdx.x;
    int tid = threadIdx.x;
    int base = g * NPG;

    for (int i = tid; i < 16 * 97; i += 128) w1s[i] = w1[i];
    for (int i = tid; i < 32 * 80; i += 128) w2s[i] = w2[i];

    if (tid < 64) {
        float v; int idx;
        if (tid < NPG) { v = xcat[(base + tid) * 97 + 96]; idx = tid; }
        else           { v = -INFINITY;                    idx = 64 + tid; }
        for (int k = 2; k <= 64; k <<= 1) {
            for (int j = k >> 1; j > 0; j >>= 1) {
                float ov = __shfl_xor(v, j);
                int   oi = __shfl_xor(idx, j);
                bool lower = (tid & j) == 0;
                bool dirA  = (tid & k) == 0;
                bool mineFirst = (v > ov) || (v == ov && idx < oi);
                bool keep = lower ? (mineFirst == dirA) : (mineFirst != dirA);
                if (!keep) { v = ov; idx = oi; }
            }
        }
        if (tid < K_TOP) sel[tid] = idx;
    }
    __syncthreads();

    for (int i = tid; i < K_TOP * 97; i += 128) {
        int j = i / 97, d = i - j * 97;
        xk[j][d] = xcat[(base + sel[j]) * 97 + d];
    }
    __syncthreads();

    for (int i = tid; i < 16 * K_TOP; i += 128) {
        int c = i / K_TOP, j = i - c * K_TOP;
        float acc = b1[c];
#pragma unroll
        for (int d = 0; d < 97; ++d) acc += xk[j][d] * w1s[c * 97 + d];
        y1[c][j] = fmaxf(acc, 0.f);
    }
    __syncthreads();

    for (int i = tid; i < 16 * 15; i += 128) {
        int c = i / 15, p = i - c * 15;
        y1p[c][p] = fmaxf(y1[c][2 * p], y1[c][2 * p + 1]);
    }
    __syncthreads();

    for (int i = tid; i < 32 * 11; i += 128) {
        int o = i / 11, p = i - o * 11;
        float acc = b2[o];
#pragma unroll
        for (int ci = 0; ci < 16; ++ci)
#pragma unroll
            for (int t = 0; t < 5; ++t)
                acc += y1p[ci][p + t] * w2s[o * 80 + ci * 5 + t];
        y2[o * 11 + p] = fmaxf(acc, 0.f);
    }
    __syncthreads();

    {
        float acc = l1b[tid];
        for (int r = 0; r < DENSE; ++r) acc += y2[r] * l1w[r * 128 + tid];
        z1[tid] = fmaxf(acc, 0.f);
    }
    __syncthreads();

    float p = z1[tid] * l2w[tid];
    for (int off = 32; off >= 1; off >>= 1) p += __shfl_xor(p, off);
    if ((tid & 63) == 0) red[tid >> 6] = p;
    __syncthreads();
    if (tid == 0) out[g] = red[0] + red[1] + l2b[0];
}

extern "C" void kernel_launch(void* const* d_in, const int* in_sizes, int n_in,
                              void* d_out, int out_size, void* d_ws, size_t ws_size,
                              hipStream_t stream) {
    const int*   z   = (const int*)d_in[0];
    const int*   ei  = (const int*)d_in[1];
    const float* zt  = (const float*)d_in[3];
    const float* W0  = (const float*)d_in[4];  const float* b0  = (const float*)d_in[5];
    const float* W1  = (const float*)d_in[6];  const float* b1g = (const float*)d_in[7];
    const float* W2  = (const float*)d_in[8];  const float* b2g = (const float*)d_in[9];
    const float* W3  = (const float*)d_in[10]; const float* b3  = (const float*)d_in[11];
    const float* c1w = (const float*)d_in[12]; const float* c1b = (const float*)d_in[13];
    const float* c2w = (const float*)d_in[14]; const float* c2b = (const float*)d_in[15];
    const float* l1w = (const float*)d_in[16]; const float* l1b = (const float*)d_in[17];
    const float* l2w = (const float*)d_in[18]; const float* l2b = (const float*)d_in[19];
    float* out = (float*)d_out;

    char* ws = (char*)d_ws;
    size_t off = 0;
    auto alloc = [&](size_t bytes) {
        void* p = ws + off;
        off += (bytes + 255) & ~(size_t)255;
        return p;
    };
    int*   deg      = (int*)alloc((size_t)N_NODES * 4);
    int*   row_ptr  = (int*)alloc((size_t)(N_NODES + 1) * 4);
    int*   cursor   = (int*)alloc((size_t)N_NODES * 4);
    int*   partials = (int*)alloc(512 * 4);
    float* dinv     = (float*)alloc((size_t)N_NODES * 4);
    int*   col      = (int*)alloc((size_t)N_EDGES * 4);
    float* hA       = (float*)alloc((size_t)N_NODES * 32 * 4);
    float* hB       = (float*)alloc((size_t)N_NODES * 32 * 4);
    float* h4       = (float*)alloc((size_t)N_NODES * 4);
    float* xcat     = (float*)alloc((size_t)N_NODES * 97 * 4);

    const int* srcp = ei;
    const int* dstp = ei + N_EDGES;

    hipMemsetAsync(deg, 0, (size_t)N_NODES * 4, stream);

    int nb = (N_NODES + 255) / 256;   // 391
    int nf = (N_NODES * 32 + 255) / 256;

    k_count_deg<<<2048, 256, 0, stream>>>(dstp, deg, N_EDGES);
    k_scanA<<<nb, 256, 0, stream>>>(deg, row_ptr, partials, N_NODES);
    k_scanB<<<1, 512, 0, stream>>>(partials, nb);
    k_scanC<<<nb, 256, 0, stream>>>(row_ptr, partials, deg, cursor, dinv, N_NODES);
    k_fill<<<2048, 256, 0, stream>>>(srcp, dstp, cursor, col, N_EDGES);

    k_embed_lin0<<<nf, 256, 0, stream>>>(z, zt, W0, dinv, hA);
    k_layer<<<nf, 256, 0, stream>>>(hA, row_ptr, col, dinv, b0, W1, xcat, 0, hB);
    k_layer<<<nf, 256, 0, stream>>>(hB, row_ptr, col, dinv, b1g, W2, xcat, 32, hA);
    k_layer_last<<<nf, 256, 0, stream>>>(hA, row_ptr, col, dinv, b2g, W3, xcat, 64, h4);
    k_prop1<<<nb, 256, 0, stream>>>(h4, row_ptr, col, dinv, b3, xcat);

    k_head<<<N_GRAPHS, 128, 0, stream>>>(xcat, c1w, c1b, c2w, c2b,
                                         l1w, l1b, l2w, l2b, out);
}

// Round 10
// 689.601 us; speedup vs baseline: 1.6580x; 1.3172x over previous
//
#include <hip/hip_runtime.h>
#include <hip/hip_bf16.h>
#include <math.h>

#define N_NODES 100000
#define N_EDGES 3200000
#define HID 32
#define K_TOP 30
#define N_GRAPHS 2000
#define NPG 50
#define TLD 97
#define DENSE 352
#define NSHARD 8
#define NPS 12500   // nodes per shard

// ---------------- CSR build (XCD-sharded) ----------------
__global__ void k_count_deg(const int* __restrict__ dst, int* __restrict__ deg, int E) {
    int shard = blockIdx.x & 7;
    int r = blockIdx.x >> 3;
    int T = (gridDim.x >> 3) * blockDim.x;
    int lo = shard * NPS, hi = lo + NPS;
    for (int e = r * blockDim.x + threadIdx.x; e < E; e += T) {
        int d = __builtin_nontemporal_load(&dst[e]);
        if (d >= lo && d < hi) atomicAdd(&deg[d], 1);
    }
}

__global__ void k_scanA(const int* __restrict__ deg, int* __restrict__ row_ptr,
                        int* __restrict__ partials, int N) {
    __shared__ int s[256];
    int tid = threadIdx.x;
    int n = blockIdx.x * 256 + tid;
    int v = (n < N) ? deg[n] : 0;
    s[tid] = v;
    __syncthreads();
    for (int off = 1; off < 256; off <<= 1) {
        int t = (tid >= off) ? s[tid - off] : 0;
        __syncthreads();
        s[tid] += t;
        __syncthreads();
    }
    if (n < N) row_ptr[n] = s[tid] - v;
    if (tid == 255) partials[blockIdx.x] = s[tid];
}

__global__ void k_scanB(int* __restrict__ partials, int nb) {
    __shared__ int s[512];
    int tid = threadIdx.x;
    int v = (tid < nb) ? partials[tid] : 0;
    s[tid] = v;
    __syncthreads();
    for (int off = 1; off < 512; off <<= 1) {
        int t = (tid >= off) ? s[tid - off] : 0;
        __syncthreads();
        s[tid] += t;
        __syncthreads();
    }
    if (tid < nb) partials[tid] = s[tid] - v;
}

__global__ void k_scanC(int* __restrict__ row_ptr, const int* __restrict__ partials,
                        const int* __restrict__ deg, int* __restrict__ cursor,
                        float* __restrict__ dinv, int N) {
    int n = blockIdx.x * 256 + threadIdx.x;
    if (n < N) {
        int r = row_ptr[n] + partials[blockIdx.x];
        row_ptr[n] = r;
        cursor[n]  = r;
        dinv[n] = rsqrtf((float)(deg[n] + 1));
    }
    if (n == 0) row_ptr[N] = N_EDGES;
}

__global__ void k_fill(const int* __restrict__ src, const int* __restrict__ dst,
                       int* __restrict__ cursor, int* __restrict__ col, int E) {
    int shard = blockIdx.x & 7;
    int r = blockIdx.x >> 3;
    int T = (gridDim.x >> 3) * blockDim.x;
    int lo = shard * NPS, hi = lo + NPS;
    for (int e = r * blockDim.x + threadIdx.x; e < E; e += T) {
        int d = __builtin_nontemporal_load(&dst[e]);
        if (d >= lo && d < hi) {
            int pos = atomicAdd(&cursor[d], 1);
            col[pos] = __builtin_nontemporal_load(&src[e]);
        }
    }
}

// ---------------- fused GCN layers ----------------
__global__ void k_embed_lin0(const int* __restrict__ z, const float* __restrict__ zt,
                             const float* __restrict__ W, const float* __restrict__ dinv,
                             float* __restrict__ hs) {
    __shared__ float Ws[32 * 32];
    int tid = threadIdx.x;
    for (int i = tid; i < 1024; i += 256) Ws[i] = W[i];
    __syncthreads();
    int gi = blockIdx.x * 256 + tid;
    if (gi >= N_NODES * 32) return;
    int n = gi >> 5, f = gi & 31;
    float v = zt[z[n] * 32 + f];
    float acc = 0.f;
#pragma unroll
    for (int f2 = 0; f2 < 32; ++f2)
        acc += __shfl(v, f2, 32) * Ws[f2 * 32 + f];
    hs[gi] = acc * dinv[n];
}

// Gather with forced MLP: explicit vals[32] keeps all 32 row-loads in flight
// (loads independent; masked lanes broadcast c=0 -> row 0, a safe address);
// adds stay in edge order (i<m predicate) so FP result is unchanged.
__device__ __forceinline__ float gather32(const float* __restrict__ hs,
                                          const int* __restrict__ col,
                                          int beg, int end, int f, float acc) {
    for (int base = beg; base < end; base += 32) {
        int rem = end - base;
        int m = rem >= 32 ? 32 : rem;
        int c = (f < m) ? col[base + f] : 0;
        float vals[32];
#pragma unroll
        for (int i = 0; i < 32; ++i) {
            int ci = __shfl(c, i, 32);
            vals[i] = hs[ci * 32 + f];
        }
        if (m == 32) {
#pragma unroll
            for (int i = 0; i < 32; ++i) acc += vals[i];
        } else {
#pragma unroll
            for (int i = 0; i < 32; ++i)
                if (i < m) acc += vals[i];
        }
    }
    return acc;
}

// one GCN layer: gather-normalize-tanh, write xcat column block, then fused
// next-layer linear: hs_out = (v @ Wnext) * dinv
__global__ void k_layer(const float* __restrict__ hs, const int* __restrict__ row_ptr,
                        const int* __restrict__ col, const float* __restrict__ dinv,
                        const float* __restrict__ b, const float* __restrict__ Wnext,
                        float* __restrict__ xcat, int coloff,
                        float* __restrict__ hs_out) {
    __shared__ float Ws[32 * 32];
    int tid = threadIdx.x;
    for (int i = tid; i < 1024; i += 256) Ws[i] = Wnext[i];
    __syncthreads();
    int gi = blockIdx.x * 256 + tid;
    if (gi >= N_NODES * 32) return;
    int n = gi >> 5, f = gi & 31;
    int beg = row_ptr[n], end = row_ptr[n + 1];
    float acc = hs[n * 32 + f];
    acc = gather32(hs, col, beg, end, f, acc);
    float v = tanhf(acc * dinv[n] + b[f]);
    xcat[n * 97 + coloff + f] = v;
    float a2 = 0.f;
#pragma unroll
    for (int f2 = 0; f2 < 32; ++f2)
        a2 += __shfl(v, f2, 32) * Ws[f2 * 32 + f];
    hs_out[n * 32 + f] = a2 * dinv[n];
}

// last 32-wide layer: same gather, but fused (v . W3) * dinv scalar reduce
__global__ void k_layer_last(const float* __restrict__ hs, const int* __restrict__ row_ptr,
                             const int* __restrict__ col, const float* __restrict__ dinv,
                             const float* __restrict__ b, const float* __restrict__ W3,
                             float* __restrict__ xcat, int coloff,
                             float* __restrict__ h4) {
    int gi = blockIdx.x * 256 + threadIdx.x;
    if (gi >= N_NODES * 32) return;
    int n = gi >> 5, f = gi & 31;
    int beg = row_ptr[n], end = row_ptr[n + 1];
    float acc = hs[n * 32 + f];
    acc = gather32(hs, col, beg, end, f, acc);
    float v = tanhf(acc * dinv[n] + b[f]);
    xcat[n * 97 + coloff + f] = v;
    float p = v * W3[f];
#pragma unroll
    for (int off = 16; off >= 1; off >>= 1) p += __shfl_xor(p, off);
    if (f == 0) h4[n] = p * dinv[n];
}

__global__ void k_prop1(const float* __restrict__ hs4, const int* __restrict__ row_ptr,
                        const int* __restrict__ col, const float* __restrict__ dinv,
                        const float* __restrict__ b3, float* __restrict__ xcat) {
    int n = blockIdx.x * blockDim.x + threadIdx.x;
    if (n >= N_NODES) return;
    int beg = row_ptr[n], end = row_ptr[n + 1];
    float acc = hs4[n];
    for (int e = beg; e < end; ++e) acc += hs4[col[e]];
    xcat[n * 97 + 96] = tanhf(acc * dinv[n] + b3[0]);
}

// ---------------- fused sort-pool + CNN + MLP head ----------------
__global__ __launch_bounds__(128) void k_head(
    const float* __restrict__ xcat,
    const float* __restrict__ w1, const float* __restrict__ b1,
    const float* __restrict__ w2, const float* __restrict__ b2,
    const float* __restrict__ l1w, const float* __restrict__ l1b,
    const float* __restrict__ l2w, const float* __restrict__ l2b,
    float* __restrict__ out) {
    __shared__ float xk[K_TOP][97];
    __shared__ float w1s[16 * 97];
    __shared__ float w2s[32 * 80];
    __shared__ float y1[16][K_TOP];
    __shared__ float y1p[16][15];
    __shared__ float y2[DENSE];
    __shared__ float z1[128];
    __shared__ int   sel[K_TOP];
    __shared__ float red[2];

    int g = blockIdx.x;
    int tid = threadIdx.x;
    int base = g * NPG;

    for (int i = tid; i < 16 * 97; i += 128) w1s[i] = w1[i];
    for (int i = tid; i < 32 * 80; i += 128) w2s[i] = w2[i];

    if (tid < 64) {
        float v; int idx;
        if (tid < NPG) { v = xcat[(base + tid) * 97 + 96]; idx = tid; }
        else           { v = -INFINITY;                    idx = 64 + tid; }
        for (int k = 2; k <= 64; k <<= 1) {
            for (int j = k >> 1; j > 0; j >>= 1) {
                float ov = __shfl_xor(v, j);
                int   oi = __shfl_xor(idx, j);
                bool lower = (tid & j) == 0;
                bool dirA  = (tid & k) == 0;
                bool mineFirst = (v > ov) || (v == ov && idx < oi);
                bool keep = lower ? (mineFirst == dirA) : (mineFirst != dirA);
                if (!keep) { v = ov; idx = oi; }
            }
        }
        if (tid < K_TOP) sel[tid] = idx;
    }
    __syncthreads();

    for (int i = tid; i < K_TOP * 97; i += 128) {
        int j = i / 97, d = i - j * 97;
        xk[j][d] = xcat[(base + sel[j]) * 97 + d];
    }
    __syncthreads();

    for (int i = tid; i < 16 * K_TOP; i += 128) {
        int c = i / K_TOP, j = i - c * K_TOP;
        float acc = b1[c];
#pragma unroll
        for (int d = 0; d < 97; ++d) acc += xk[j][d] * w1s[c * 97 + d];
        y1[c][j] = fmaxf(acc, 0.f);
    }
    __syncthreads();

    for (int i = tid; i < 16 * 15; i += 128) {
        int c = i / 15, p = i - c * 15;
        y1p[c][p] = fmaxf(y1[c][2 * p], y1[c][2 * p + 1]);
    }
    __syncthreads();

    for (int i = tid; i < 32 * 11; i += 128) {
        int o = i / 11, p = i - o * 11;
        float acc = b2[o];
#pragma unroll
        for (int ci = 0; ci < 16; ++ci)
#pragma unroll
            for (int t = 0; t < 5; ++t)
                acc += y1p[ci][p + t] * w2s[o * 80 + ci * 5 + t];
        y2[o * 11 + p] = fmaxf(acc, 0.f);
    }
    __syncthreads();

    {
        float acc = l1b[tid];
        for (int r = 0; r < DENSE; ++r) acc += y2[r] * l1w[r * 128 + tid];
        z1[tid] = fmaxf(acc, 0.f);
    }
    __syncthreads();

    float p = z1[tid] * l2w[tid];
    for (int off = 32; off >= 1; off >>= 1) p += __shfl_xor(p, off);
    if ((tid & 63) == 0) red[tid >> 6] = p;
    __syncthreads();
    if (tid == 0) out[g] = red[0] + red[1] + l2b[0];
}

extern "C" void kernel_launch(void* const* d_in, const int* in_sizes, int n_in,
                              void* d_out, int out_size, void* d_ws, size_t ws_size,
                              hipStream_t stream) {
    const int*   z   = (const int*)d_in[0];
    const int*   ei  = (const int*)d_in[1];
    const float* zt  = (const float*)d_in[3];
    const float* W0  = (const float*)d_in[4];  const float* b0  = (const float*)d_in[5];
    const float* W1  = (const float*)d_in[6];  const float* b1g = (const float*)d_in[7];
    const float* W2  = (const float*)d_in[8];  const float* b2g = (const float*)d_in[9];
    const float* W3  = (const float*)d_in[10]; const float* b3  = (const float*)d_in[11];
    const float* c1w = (const float*)d_in[12]; const float* c1b = (const float*)d_in[13];
    const float* c2w = (const float*)d_in[14]; const float* c2b = (const float*)d_in[15];
    const float* l1w = (const float*)d_in[16]; const float* l1b = (const float*)d_in[17];
    const float* l2w = (const float*)d_in[18]; const float* l2b = (const float*)d_in[19];
    float* out = (float*)d_out;

    char* ws = (char*)d_ws;
    size_t off = 0;
    auto alloc = [&](size_t bytes) {
        void* p = ws + off;
        off += (bytes + 255) & ~(size_t)255;
        return p;
    };
    int*   deg      = (int*)alloc((size_t)N_NODES * 4);
    int*   row_ptr  = (int*)alloc((size_t)(N_NODES + 1) * 4);
    int*   cursor   = (int*)alloc((size_t)N_NODES * 4);
    int*   partials = (int*)alloc(512 * 4);
    float* dinv     = (float*)alloc((size_t)N_NODES * 4);
    int*   col      = (int*)alloc((size_t)N_EDGES * 4);
    float* hA       = (float*)alloc((size_t)N_NODES * 32 * 4);
    float* hB       = (float*)alloc((size_t)N_NODES * 32 * 4);
    float* h4       = (float*)alloc((size_t)N_NODES * 4);
    float* xcat     = (float*)alloc((size_t)N_NODES * 97 * 4);

    const int* srcp = ei;
    const int* dstp = ei + N_EDGES;

    hipMemsetAsync(deg, 0, (size_t)N_NODES * 4, stream);

    int nb = (N_NODES + 255) / 256;   // 391
    int nf = (N_NODES * 32 + 255) / 256;

    k_count_deg<<<2048, 256, 0, stream>>>(dstp, deg, N_EDGES);
    k_scanA<<<nb, 256, 0, stream>>>(deg, row_ptr, partials, N_NODES);
    k_scanB<<<1, 512, 0, stream>>>(partials, nb);
    k_scanC<<<nb, 256, 0, stream>>>(row_ptr, partials, deg, cursor, dinv, N_NODES);
    k_fill<<<2048, 256, 0, stream>>>(srcp, dstp, cursor, col, N_EDGES);

    k_embed_lin0<<<nf, 256, 0, stream>>>(z, zt, W0, dinv, hA);
    k_layer<<<nf, 256, 0, stream>>>(hA, row_ptr, col, dinv, b0, W1, xcat, 0, hB);
    k_layer<<<nf, 256, 0, stream>>>(hB, row_ptr, col, dinv, b1g, W2, xcat, 32, hA);
    k_layer_last<<<nf, 256, 0, stream>>>(hA, row_ptr, col, dinv, b2g, W3, xcat, 64, h4);
    k_prop1<<<nb, 256, 0, stream>>>(h4, row_ptr, col, dinv, b3, xcat);

    k_head<<<N_GRAPHS, 128, 0, stream>>>(xcat, c1w, c1b, c2w, c2b,
                                         l1w, l1b, l2w, l2b, out);
}

// Round 12
// 490.522 us; speedup vs baseline: 2.3309x; 1.4059x over previous
//
#include <hip/hip_runtime.h>
#include <hip/hip_bf16.h>
#include <math.h>

#define N_NODES 100000
#define N_EDGES 3200000
#define HID 32
#define K_TOP 30
#define N_GRAPHS 2000
#define NPG 50
#define TLD 97
#define DENSE 352

#define NB 256            // dst-range buckets
#define NPB 391           // nodes per bucket (ceil(100000/256)); last bucket short
#define CAP 14336         // bucket capacity (mean 12512, sigma ~112 -> +16 sigma)
#define CE  ((N_EDGES + 2047) / 2048)   // edges per k_bucket block

// ---------------- CSR build: atomic-light bucket partition ----------------
// Pass 1: 2048 blocks; each owns a contiguous edge range. LDS histogram over
// 256 buckets -> one global atomicAdd per (block,bucket) for buffer base ->
// second sweep (L2-hot re-read) writes (dst,src) pairs contiguously.
__global__ __launch_bounds__(256) void k_bucket(const int* __restrict__ dst,
                                                const int* __restrict__ src,
                                                int* __restrict__ gcount,
                                                int2* __restrict__ buf) {
    __shared__ int hist[NB];
    __shared__ int base_l[NB];
    int tid = threadIdx.x;
    int e0 = blockIdx.x * CE;
    int e1 = e0 + CE; if (e1 > N_EDGES) e1 = N_EDGES;
    hist[tid] = 0;
    __syncthreads();
    for (int e = e0 + tid; e < e1; e += 256) {
        int d = dst[e];
        atomicAdd(&hist[d / NPB], 1);
    }
    __syncthreads();
    int cnt = hist[tid];
    base_l[tid] = cnt ? atomicAdd(&gcount[tid], cnt) : 0;
    __syncthreads();
    hist[tid] = 0;            // reuse as local cursor
    __syncthreads();
    for (int e = e0 + tid; e < e1; e += 256) {
        int d = dst[e];
        int s = src[e];
        int b = d / NPB;
        int r = atomicAdd(&hist[b], 1);
        buf[b * CAP + base_l[b] + r] = int2{d, s};
    }
}

// Exclusive scan of 256 bucket counts -> bucket_base; also row_ptr[N] = E.
__global__ void k_scan256(const int* __restrict__ gcount, int* __restrict__ bucket_base,
                          int* __restrict__ row_ptr) {
    __shared__ int s[NB];
    int tid = threadIdx.x;
    int v = gcount[tid];
    s[tid] = v;
    __syncthreads();
    for (int off = 1; off < NB; off <<= 1) {
        int t = (tid >= off) ? s[tid - off] : 0;
        __syncthreads();
        s[tid] += t;
        __syncthreads();
    }
    bucket_base[tid] = s[tid] - v;
    if (tid == NB - 1) row_ptr[N_NODES] = s[tid];   // == N_EDGES
}

// Pass 2: one block per bucket. Per-node LDS histogram -> LDS prefix scan ->
// row_ptr/dinv slices; then LDS-cursor fill of col. Zero global atomics.
__global__ __launch_bounds__(512) void k_build(const int2* __restrict__ buf,
                                               const int* __restrict__ gcount,
                                               const int* __restrict__ bucket_base,
                                               int* __restrict__ row_ptr,
                                               float* __restrict__ dinv,
                                               int* __restrict__ col) {
    __shared__ int s[512];
    int k = blockIdx.x;
    int tid = threadIdx.x;
    int lo = k * NPB;
    int cnt = gcount[k];
    int rowbase = bucket_base[k];
    const int2* b = buf + k * CAP;
    s[tid] = 0;
    __syncthreads();
    for (int i = tid; i < cnt; i += 512)
        atomicAdd(&s[b[i].x - lo], 1);
    __syncthreads();
    int mydeg = s[tid];
    bool valid = (tid < NPB) && (lo + tid < N_NODES);
    if (valid) dinv[lo + tid] = rsqrtf((float)(mydeg + 1));
    // inclusive Hillis-Steele scan over 512
    for (int off = 1; off < 512; off <<= 1) {
        int t = (tid >= off) ? s[tid - off] : 0;
        __syncthreads();
        s[tid] += t;
        __syncthreads();
    }
    int excl = s[tid] - mydeg;
    if (valid) row_ptr[lo + tid] = rowbase + excl;
    __syncthreads();
    s[tid] = excl;            // reuse as per-node local cursor
    __syncthreads();
    for (int i = tid; i < cnt; i += 512) {
        int2 e = b[i];
        int r = atomicAdd(&s[e.x - lo], 1);
        col[rowbase + r] = e.y;
    }
}

// ---------------- fused GCN layers ----------------
__global__ void k_embed_lin0(const int* __restrict__ z, const float* __restrict__ zt,
                             const float* __restrict__ W, const float* __restrict__ dinv,
                             float* __restrict__ hs) {
    __shared__ float Ws[32 * 32];
    int tid = threadIdx.x;
    for (int i = tid; i < 1024; i += 256) Ws[i] = W[i];
    __syncthreads();
    int gi = blockIdx.x * 256 + tid;
    if (gi >= N_NODES * 32) return;
    int n = gi >> 5, f = gi & 31;
    float v = zt[z[n] * 32 + f];
    float acc = 0.f;
#pragma unroll
    for (int f2 = 0; f2 < 32; ++f2)
        acc += __shfl(v, f2, 32) * Ws[f2 * 32 + f];
    hs[gi] = acc * dinv[n];
}

// Gather with forced MLP: explicit vals[32] keeps all 32 row-loads in flight.
__device__ __forceinline__ float gather32(const float* __restrict__ hs,
                                          const int* __restrict__ col,
                                          int beg, int end, int f, float acc) {
    for (int base = beg; base < end; base += 32) {
        int rem = end - base;
        int m = rem >= 32 ? 32 : rem;
        int c = (f < m) ? col[base + f] : 0;
        float vals[32];
#pragma unroll
        for (int i = 0; i < 32; ++i) {
            int ci = __shfl(c, i, 32);
            vals[i] = hs[ci * 32 + f];
        }
        if (m == 32) {
#pragma unroll
            for (int i = 0; i < 32; ++i) acc += vals[i];
        } else {
#pragma unroll
            for (int i = 0; i < 32; ++i)
                if (i < m) acc += vals[i];
        }
    }
    return acc;
}

__global__ void k_layer(const float* __restrict__ hs, const int* __restrict__ row_ptr,
                        const int* __restrict__ col, const float* __restrict__ dinv,
                        const float* __restrict__ b, const float* __restrict__ Wnext,
                        float* __restrict__ xcat, int coloff,
                        float* __restrict__ hs_out) {
    __shared__ float Ws[32 * 32];
    int tid = threadIdx.x;
    for (int i = tid; i < 1024; i += 256) Ws[i] = Wnext[i];
    __syncthreads();
    int gi = blockIdx.x * 256 + tid;
    if (gi >= N_NODES * 32) return;
    int n = gi >> 5, f = gi & 31;
    int beg = row_ptr[n], end = row_ptr[n + 1];
    float acc = hs[n * 32 + f];
    acc = gather32(hs, col, beg, end, f, acc);
    float v = tanhf(acc * dinv[n] + b[f]);
    xcat[n * 97 + coloff + f] = v;
    float a2 = 0.f;
#pragma unroll
    for (int f2 = 0; f2 < 32; ++f2)
        a2 += __shfl(v, f2, 32) * Ws[f2 * 32 + f];
    hs_out[n * 32 + f] = a2 * dinv[n];
}

__global__ void k_layer_last(const float* __restrict__ hs, const int* __restrict__ row_ptr,
                             const int* __restrict__ col, const float* __restrict__ dinv,
                             const float* __restrict__ b, const float* __restrict__ W3,
                             float* __restrict__ xcat, int coloff,
                             float* __restrict__ h4) {
    int gi = blockIdx.x * 256 + threadIdx.x;
    if (gi >= N_NODES * 32) return;
    int n = gi >> 5, f = gi & 31;
    int beg = row_ptr[n], end = row_ptr[n + 1];
    float acc = hs[n * 32 + f];
    acc = gather32(hs, col, beg, end, f, acc);
    float v = tanhf(acc * dinv[n] + b[f]);
    xcat[n * 97 + coloff + f] = v;
    float p = v * W3[f];
#pragma unroll
    for (int off = 16; off >= 1; off >>= 1) p += __shfl_xor(p, off);
    if (f == 0) h4[n] = p * dinv[n];
}

// wave-cooperative final propagation: 32 lanes per node, coalesced col reads,
// parallel hs4 gathers, shfl tree-reduce.
__global__ void k_prop1w(const float* __restrict__ hs4, const int* __restrict__ row_ptr,
                         const int* __restrict__ col, const float* __restrict__ dinv,
                         const float* __restrict__ b3, float* __restrict__ xcat) {
    int gi = blockIdx.x * 256 + threadIdx.x;
    if (gi >= N_NODES * 32) return;
    int n = gi >> 5, lane = gi & 31;
    int beg = row_ptr[n], end = row_ptr[n + 1];
    float part = 0.f;
    for (int e = beg + lane; e < end; e += 32)
        part += hs4[col[e]];
#pragma unroll
    for (int off = 16; off >= 1; off >>= 1) part += __shfl_xor(part, off);
    if (lane == 0) {
        float acc = hs4[n] + part;
        xcat[n * 97 + 96] = tanhf(acc * dinv[n] + b3[0]);
    }
}

// ---------------- fused sort-pool + CNN + MLP head ----------------
__global__ __launch_bounds__(128) void k_head(
    const float* __restrict__ xcat,
    const float* __restrict__ w1, const float* __restrict__ b1,
    const float* __restrict__ w2, const float* __restrict__ b2,
    const float* __restrict__ l1w, const float* __restrict__ l1b,
    const float* __restrict__ l2w, const float* __restrict__ l2b,
    float* __restrict__ out) {
    __shared__ float xk[K_TOP][97];
    __shared__ float w1s[16 * 97];
    __shared__ float w2s[32 * 80];
    __shared__ float y1[16][K_TOP];
    __shared__ float y1p[16][15];
    __shared__ float y2[DENSE];
    __shared__ float z1[128];
    __shared__ int   sel[K_TOP];
    __shared__ float red[2];

    int g = blockIdx.x;
    int tid = threadIdx.x;
    int base = g * NPG;

    for (int i = tid; i < 16 * 97; i += 128) w1s[i] = w1[i];
    for (int i = tid; i < 32 * 80; i += 128) w2s[i] = w2[i];

    if (tid < 64) {
        float v; int idx;
        if (tid < NPG) { v = xcat[(base + tid) * 97 + 96]; idx = tid; }
        else           { v = -INFINITY;                    idx = 64 + tid; }
        for (int k = 2; k <= 64; k <<= 1) {
            for (int j = k >> 1; j > 0; j >>= 1) {
                float ov = __shfl_xor(v, j);
                int   oi = __shfl_xor(idx, j);
                bool lower = (tid & j) == 0;
                bool dirA  = (tid & k) == 0;
                bool mineFirst = (v > ov) || (v == ov && idx < oi);
                bool keep = lower ? (mineFirst == dirA) : (mineFirst != dirA);
                if (!keep) { v = ov; idx = oi; }
            }
        }
        if (tid < K_TOP) sel[tid] = idx;
    }
    __syncthreads();

    for (int i = tid; i < K_TOP * 97; i += 128) {
        int j = i / 97, d = i - j * 97;
        xk[j][d] = xcat[(base + sel[j]) * 97 + d];
    }
    __syncthreads();

    for (int i = tid; i < 16 * K_TOP; i += 128) {
        int c = i / K_TOP, j = i - c * K_TOP;
        float acc = b1[c];
#pragma unroll
        for (int d = 0; d < 97; ++d) acc += xk[j][d] * w1s[c * 97 + d];
        y1[c][j] = fmaxf(acc, 0.f);
    }
    __syncthreads();

    for (int i = tid; i < 16 * 15; i += 128) {
        int c = i / 15, p = i - c * 15;
        y1p[c][p] = fmaxf(y1[c][2 * p], y1[c][2 * p + 1]);
    }
    __syncthreads();

    for (int i = tid; i < 32 * 11; i += 128) {
        int o = i / 11, p = i - o * 11;
        float acc = b2[o];
#pragma unroll
        for (int ci = 0; ci < 16; ++ci)
#pragma unroll
            for (int t = 0; t < 5; ++t)
                acc += y1p[ci][p + t] * w2s[o * 80 + ci * 5 + t];
        y2[o * 11 + p] = fmaxf(acc, 0.f);
    }
    __syncthreads();

    {
        float acc = l1b[tid];
        for (int r = 0; r < DENSE; ++r) acc += y2[r] * l1w[r * 128 + tid];
        z1[tid] = fmaxf(acc, 0.f);
    }
    __syncthreads();

    float p = z1[tid] * l2w[tid];
    for (int off = 32; off >= 1; off >>= 1) p += __shfl_xor(p, off);
    if ((tid & 63) == 0) red[tid >> 6] = p;
    __syncthreads();
    if (tid == 0) out[g] = red[0] + red[1] + l2b[0];
}

extern "C" void kernel_launch(void* const* d_in, const int* in_sizes, int n_in,
                              void* d_out, int out_size, void* d_ws, size_t ws_size,
                              hipStream_t stream) {
    const int*   z   = (const int*)d_in[0];
    const int*   ei  = (const int*)d_in[1];
    const float* zt  = (const float*)d_in[3];
    const float* W0  = (const float*)d_in[4];  const float* b0  = (const float*)d_in[5];
    const float* W1  = (const float*)d_in[6];  const float* b1g = (const float*)d_in[7];
    const float* W2  = (const float*)d_in[8];  const float* b2g = (const float*)d_in[9];
    const float* W3  = (const float*)d_in[10]; const float* b3  = (const float*)d_in[11];
    const float* c1w = (const float*)d_in[12]; const float* c1b = (const float*)d_in[13];
    const float* c2w = (const float*)d_in[14]; const float* c2b = (const float*)d_in[15];
    const float* l1w = (const float*)d_in[16]; const float* l1b = (const float*)d_in[17];
    const float* l2w = (const float*)d_in[18]; const float* l2b = (const float*)d_in[19];
    float* out = (float*)d_out;

    char* ws = (char*)d_ws;
    size_t off = 0;
    auto alloc = [&](size_t bytes) {
        void* p = ws + off;
        off += (bytes + 255) & ~(size_t)255;
        return p;
    };
    int*   row_ptr     = (int*)alloc((size_t)(N_NODES + 1) * 4);
    float* dinv        = (float*)alloc((size_t)N_NODES * 4);
    int*   col         = (int*)alloc((size_t)N_EDGES * 4);
    int*   gcount      = (int*)alloc((size_t)NB * 4);
    int*   bucket_base = (int*)alloc((size_t)NB * 4);
    int2*  bucketbuf   = (int2*)alloc((size_t)NB * CAP * 8);
    float* hA          = (float*)alloc((size_t)N_NODES * 32 * 4);
    float* hB          = (float*)alloc((size_t)N_NODES * 32 * 4);
    float* h4          = (float*)alloc((size_t)N_NODES * 4);
    float* xcat        = (float*)alloc((size_t)N_NODES * 97 * 4);

    const int* srcp = ei;
    const int* dstp = ei + N_EDGES;

    hipMemsetAsync(gcount, 0, (size_t)NB * 4, stream);

    int nf = (N_NODES * 32 + 255) / 256;   // 12500

    k_bucket<<<2048, 256, 0, stream>>>(dstp, srcp, gcount, bucketbuf);
    k_scan256<<<1, NB, 0, stream>>>(gcount, bucket_base, row_ptr);
    k_build<<<NB, 512, 0, stream>>>(bucketbuf, gcount, bucket_base, row_ptr, dinv, col);

    k_embed_lin0<<<nf, 256, 0, stream>>>(z, zt, W0, dinv, hA);
    k_layer<<<nf, 256, 0, stream>>>(hA, row_ptr, col, dinv, b0, W1, xcat, 0, hB);
    k_layer<<<nf, 256, 0, stream>>>(hB, row_ptr, col, dinv, b1g, W2, xcat, 32, hA);
    k_layer_last<<<nf, 256, 0, stream>>>(hA, row_ptr, col, dinv, b2g, W3, xcat, 64, h4);
    k_prop1w<<<nf, 256, 0, stream>>>(h4, row_ptr, col, dinv, b3, xcat);

    k_head<<<N_GRAPHS, 128, 0, stream>>>(xcat, c1w, c1b, c2w, c2b,
                                         l1w, l1b, l2w, l2b, out);
}

// Round 16
// 455.760 us; speedup vs baseline: 2.5087x; 1.0763x over previous
//
#include <hip/hip_runtime.h>
#include <hip/hip_bf16.h>
#include <math.h>

#define N_NODES 100000
#define N_EDGES 3200000
#define HID 32
#define K_TOP 30
#define N_GRAPHS 2000
#define NPG 50
#define TLD 97
#define DENSE 352

#define NB 256            // dst-range buckets
#define NPB 391           // nodes per bucket (ceil(100000/256)); last bucket short
#define CAP 14336         // bucket capacity (mean 12512, sigma ~112 -> +16 sigma)
#define NBLK 512          // k_bucket blocks: CE=6250 -> ~24 edges/bucket/block
#define CE  ((N_EDGES + NBLK - 1) / NBLK)

// ---------------- CSR build: packed bucket partition ----------------
// Pass 1: NBLK blocks; each owns a contiguous edge range. LDS histogram over
// 256 dst-range buckets -> one global atomicAdd per (block,bucket) -> second
// sweep (L2-hot re-read) writes PACKED edges ((d-lo)<<17 | src, 4B) into the
// bucket buffer. Longer runs (~96B) + 4B payload kill write amplification.
__global__ __launch_bounds__(256) void k_bucket(const int* __restrict__ dst,
                                                const int* __restrict__ src,
                                                int* __restrict__ gcount,
                                                int* __restrict__ buf) {
    __shared__ int hist[NB];
    __shared__ int base_l[NB];
    int tid = threadIdx.x;
    int e0 = blockIdx.x * CE;
    int e1 = e0 + CE; if (e1 > N_EDGES) e1 = N_EDGES;
    hist[tid] = 0;
    __syncthreads();
    for (int e = e0 + tid; e < e1; e += 256) {
        int d = dst[e];
        atomicAdd(&hist[d / NPB], 1);
    }
    __syncthreads();
    int cnt = hist[tid];
    base_l[tid] = cnt ? atomicAdd(&gcount[tid], cnt) : 0;
    __syncthreads();
    hist[tid] = 0;            // reuse as local cursor
    __syncthreads();
    for (int e = e0 + tid; e < e1; e += 256) {
        int d = dst[e];
        int s = src[e];
        int b = d / NPB;
        int r = atomicAdd(&hist[b], 1);
        buf[b * CAP + base_l[b] + r] = ((d - b * NPB) << 17) | s;
    }
}

// Pass 2: one block per bucket. Per-block LDS re-scan of the 256 bucket
// counts (replaces separate k_scan256 launch), then per-node LDS histogram ->
// LDS prefix scan -> row_ptr/dinv slices -> LDS-cursor fill of col.
__global__ __launch_bounds__(512) void k_build(const int* __restrict__ buf,
                                               const int* __restrict__ gcount,
                                               int* __restrict__ row_ptr,
                                               float* __restrict__ dinv,
                                               int* __restrict__ col) {
    __shared__ int sb[NB];
    __shared__ int s[512];
    int k = blockIdx.x;
    int tid = threadIdx.x;
    if (tid < NB) sb[tid] = gcount[tid];
    __syncthreads();
    for (int off = 1; off < NB; off <<= 1) {
        int t = (tid < NB && tid >= off) ? sb[tid - off] : 0;
        __syncthreads();
        if (tid < NB) sb[tid] += t;
        __syncthreads();
    }
    int rowbase = (k == 0) ? 0 : sb[k - 1];
    int cnt = gcount[k];
    if (k == NB - 1 && tid == 0) row_ptr[N_NODES] = sb[NB - 1];   // == N_EDGES
    int lo = k * NPB;
    const int* b = buf + k * CAP;
    s[tid] = 0;
    __syncthreads();
    for (int i = tid; i < cnt; i += 512)
        atomicAdd(&s[b[i] >> 17], 1);
    __syncthreads();
    int mydeg = s[tid];
    bool valid = (tid < NPB) && (lo + tid < N_NODES);
    if (valid) dinv[lo + tid] = rsqrtf((float)(mydeg + 1));
    // inclusive Hillis-Steele scan over 512
    for (int off = 1; off < 512; off <<= 1) {
        int t = (tid >= off) ? s[tid - off] : 0;
        __syncthreads();
        s[tid] += t;
        __syncthreads();
    }
    int excl = s[tid] - mydeg;
    if (valid) row_ptr[lo + tid] = rowbase + excl;
    __syncthreads();
    s[tid] = excl;            // reuse as per-node local cursor
    __syncthreads();
    for (int i = tid; i < cnt; i += 512) {
        int v = b[i];
        int r = atomicAdd(&s[v >> 17], 1);
        col[rowbase + r] = v & 0x1FFFF;
    }
}

// ---------------- fused GCN layers ----------------
__global__ void k_embed_lin0(const int* __restrict__ z, const float* __restrict__ zt,
                             const float* __restrict__ W, const float* __restrict__ dinv,
                             float* __restrict__ hs) {
    __shared__ float Ws[32 * 32];
    int tid = threadIdx.x;
    for (int i = tid; i < 1024; i += 256) Ws[i] = W[i];
    __syncthreads();
    int gi = blockIdx.x * 256 + tid;
    if (gi >= N_NODES * 32) return;
    int n = gi >> 5, f = gi & 31;
    float v = zt[z[n] * 32 + f];
    float acc = 0.f;
#pragma unroll
    for (int f2 = 0; f2 < 32; ++f2)
        acc += __shfl(v, f2, 32) * Ws[f2 * 32 + f];
    hs[gi] = acc * dinv[n];
}

// Gather with forced MLP: explicit vals[32] keeps all 32 row-loads in flight.
__device__ __forceinline__ float gather32(const float* __restrict__ hs,
                                          const int* __restrict__ col,
                                          int beg, int end, int f, float acc) {
    for (int base = beg; base < end; base += 32) {
        int rem = end - base;
        int m = rem >= 32 ? 32 : rem;
        int c = (f < m) ? col[base + f] : 0;
        float vals[32];
#pragma unroll
        for (int i = 0; i < 32; ++i) {
            int ci = __shfl(c, i, 32);
            vals[i] = hs[ci * 32 + f];
        }
        if (m == 32) {
#pragma unroll
            for (int i = 0; i < 32; ++i) acc += vals[i];
        } else {
#pragma unroll
            for (int i = 0; i < 32; ++i)
                if (i < m) acc += vals[i];
        }
    }
    return acc;
}

__global__ void k_layer(const float* __restrict__ hs, const int* __restrict__ row_ptr,
                        const int* __restrict__ col, const float* __restrict__ dinv,
                        const float* __restrict__ b, const float* __restrict__ Wnext,
                        float* __restrict__ xcat, int coloff,
                        float* __restrict__ hs_out) {
    __shared__ float Ws[32 * 32];
    int tid = threadIdx.x;
    for (int i = tid; i < 1024; i += 256) Ws[i] = Wnext[i];
    __syncthreads();
    int gi = blockIdx.x * 256 + tid;
    if (gi >= N_NODES * 32) return;
    int n = gi >> 5, f = gi & 31;
    int beg = row_ptr[n], end = row_ptr[n + 1];
    float acc = hs[n * 32 + f];
    acc = gather32(hs, col, beg, end, f, acc);
    float v = tanhf(acc * dinv[n] + b[f]);
    xcat[n * 97 + coloff + f] = v;
    float a2 = 0.f;
#pragma unroll
    for (int f2 = 0; f2 < 32; ++f2)
        a2 += __shfl(v, f2, 32) * Ws[f2 * 32 + f];
    hs_out[n * 32 + f] = a2 * dinv[n];
}

__global__ void k_layer_last(const float* __restrict__ hs, const int* __restrict__ row_ptr,
                             const int* __restrict__ col, const float* __restrict__ dinv,
                             const float* __restrict__ b, const float* __restrict__ W3,
                             float* __restrict__ xcat, int coloff,
                             float* __restrict__ h4) {
    int gi = blockIdx.x * 256 + threadIdx.x;
    if (gi >= N_NODES * 32) return;
    int n = gi >> 5, f = gi & 31;
    int beg = row_ptr[n], end = row_ptr[n + 1];
    float acc = hs[n * 32 + f];
    acc = gather32(hs, col, beg, end, f, acc);
    float v = tanhf(acc * dinv[n] + b[f]);
    xcat[n * 97 + coloff + f] = v;
    float p = v * W3[f];
#pragma unroll
    for (int off = 16; off >= 1; off >>= 1) p += __shfl_xor(p, off);
    if (f == 0) h4[n] = p * dinv[n];
}

// wave-cooperative final propagation: 32 lanes per node, coalesced col reads,
// parallel hs4 gathers, shfl tree-reduce.
__global__ void k_prop1w(const float* __restrict__ hs4, const int* __restrict__ row_ptr,
                         const int* __restrict__ col, const float* __restrict__ dinv,
                         const float* __restrict__ b3, float* __restrict__ xcat) {
    int gi = blockIdx.x * 256 + threadIdx.x;
    if (gi >= N_NODES * 32) return;
    int n = gi >> 5, lane = gi & 31;
    int beg = row_ptr[n], end = row_ptr[n + 1];
    float part = 0.f;
    for (int e = beg + lane; e < end; e += 32)
        part += hs4[col[e]];
#pragma unroll
    for (int off = 16; off >= 1; off >>= 1) part += __shfl_xor(part, off);
    if (lane == 0) {
        float acc = hs4[n] + part;
        xcat[n * 97 + 96] = tanhf(acc * dinv[n] + b3[0]);
    }
}

// ---------------- fused sort-pool + CNN + MLP head ----------------
__global__ __launch_bounds__(128) void k_head(
    const float* __restrict__ xcat,
    const float* __restrict__ w1, const float* __restrict__ b1,
    const float* __restrict__ w2, const float* __restrict__ b2,
    const float* __restrict__ l1w, const float* __restrict__ l1b,
    const float* __restrict__ l2w, const float* __restrict__ l2b,
    float* __restrict__ out) {
    __shared__ float xk[K_TOP][97];
    __shared__ float w1s[16 * 97];
    __shared__ float w2s[32 * 80];
    __shared__ float y1[16][K_TOP];
    __shared__ float y1p[16][15];
    __shared__ float y2[DENSE];
    __shared__ float z1[128];
    __shared__ int   sel[K_TOP];
    __shared__ float red[2];

    int g = blockIdx.x;
    int tid = threadIdx.x;
    int base = g * NPG;

    for (int i = tid; i < 16 * 97; i += 128) w1s[i] = w1[i];
    for (int i = tid; i < 32 * 80; i += 128) w2s[i] = w2[i];

    if (tid < 64) {
        float v; int idx;
        if (tid < NPG) { v = xcat[(base + tid) * 97 + 96]; idx = tid; }
        else           { v = -INFINITY;                    idx = 64 + tid; }
        for (int k = 2; k <= 64; k <<= 1) {
            for (int j = k >> 1; j > 0; j >>= 1) {
                float ov = __shfl_xor(v, j);
                int   oi = __shfl_xor(idx, j);
                bool lower = (tid & j) == 0;
                bool dirA  = (tid & k) == 0;
                bool mineFirst = (v > ov) || (v == ov && idx < oi);
                bool keep = lower ? (mineFirst == dirA) : (mineFirst != dirA);
                if (!keep) { v = ov; idx = oi; }
            }
        }
        if (tid < K_TOP) sel[tid] = idx;
    }
    __syncthreads();

    for (int i = tid; i < K_TOP * 97; i += 128) {
        int j = i / 97, d = i - j * 97;
        xk[j][d] = xcat[(base + sel[j]) * 97 + d];
    }
    __syncthreads();

    for (int i = tid; i < 16 * K_TOP; i += 128) {
        int c = i / K_TOP, j = i - c * K_TOP;
        float acc = b1[c];
#pragma unroll
        for (int d = 0; d < 97; ++d) acc += xk[j][d] * w1s[c * 97 + d];
        y1[c][j] = fmaxf(acc, 0.f);
    }
    __syncthreads();

    for (int i = tid; i < 16 * 15; i += 128) {
        int c = i / 15, p = i - c * 15;
        y1p[c][p] = fmaxf(y1[c][2 * p], y1[c][2 * p + 1]);
    }
    __syncthreads();

    for (int i = tid; i < 32 * 11; i += 128) {
        int o = i / 11, p = i - o * 11;
        float acc = b2[o];
#pragma unroll
        for (int ci = 0; ci < 16; ++ci)
#pragma unroll
            for (int t = 0; t < 5; ++t)
                acc += y1p[ci][p + t] * w2s[o * 80 + ci * 5 + t];
        y2[o * 11 + p] = fmaxf(acc, 0.f);
    }
    __syncthreads();

    {
        float acc = l1b[tid];
        for (int r = 0; r < DENSE; ++r) acc += y2[r] * l1w[r * 128 + tid];
        z1[tid] = fmaxf(acc, 0.f);
    }
    __syncthreads();

    float p = z1[tid] * l2w[tid];
    for (int off = 32; off >= 1; off >>= 1) p += __shfl_xor(p, off);
    if ((tid & 63) == 0) red[tid >> 6] = p;
    __syncthreads();
    if (tid == 0) out[g] = red[0] + red[1] + l2b[0];
}

extern "C" void kernel_launch(void* const* d_in, const int* in_sizes, int n_in,
                              void* d_out, int out_size, void* d_ws, size_t ws_size,
                              hipStream_t stream) {
    const int*   z   = (const int*)d_in[0];
    const int*   ei  = (const int*)d_in[1];
    const float* zt  = (const float*)d_in[3];
    const float* W0  = (const float*)d_in[4];  const float* b0  = (const float*)d_in[5];
    const float* W1  = (const float*)d_in[6];  const float* b1g = (const float*)d_in[7];
    const float* W2  = (const float*)d_in[8];  const float* b2g = (const float*)d_in[9];
    const float* W3  = (const float*)d_in[10]; const float* b3  = (const float*)d_in[11];
    const float* c1w = (const float*)d_in[12]; const float* c1b = (const float*)d_in[13];
    const float* c2w = (const float*)d_in[14]; const float* c2b = (const float*)d_in[15];
    const float* l1w = (const float*)d_in[16]; const float* l1b = (const float*)d_in[17];
    const float* l2w = (const float*)d_in[18]; const float* l2b = (const float*)d_in[19];
    float* out = (float*)d_out;

    char* ws = (char*)d_ws;
    size_t off = 0;
    auto alloc = [&](size_t bytes) {
        void* p = ws + off;
        off += (bytes + 255) & ~(size_t)255;
        return p;
    };
    int*   row_ptr   = (int*)alloc((size_t)(N_NODES + 1) * 4);
    float* dinv      = (float*)alloc((size_t)N_NODES * 4);
    int*   col       = (int*)alloc((size_t)N_EDGES * 4);
    int*   gcount    = (int*)alloc((size_t)NB * 4);
    int*   bucketbuf = (int*)alloc((size_t)NB * CAP * 4);
    float* hA        = (float*)alloc((size_t)N_NODES * 32 * 4);
    float* hB        = (float*)alloc((size_t)N_NODES * 32 * 4);
    float* h4        = (float*)alloc((size_t)N_NODES * 4);
    float* xcat      = (float*)alloc((size_t)N_NODES * 97 * 4);

    const int* srcp = ei;
    const int* dstp = ei + N_EDGES;

    hipMemsetAsync(gcount, 0, (size_t)NB * 4, stream);

    int nf = (N_NODES * 32 + 255) / 256;   // 12500

    k_bucket<<<NBLK, 256, 0, stream>>>(dstp, srcp, gcount, bucketbuf);
    k_build<<<NB, 512, 0, stream>>>(bucketbuf, gcount, row_ptr, dinv, col);

    k_embed_lin0<<<nf, 256, 0, stream>>>(z, zt, W0, dinv, hA);
    k_layer<<<nf, 256, 0, stream>>>(hA, row_ptr, col, dinv, b0, W1, xcat, 0, hB);
    k_layer<<<nf, 256, 0, stream>>>(hB, row_ptr, col, dinv, b1g, W2, xcat, 32, hA);
    k_layer_last<<<nf, 256, 0, stream>>>(hA, row_ptr, col, dinv, b2g, W3, xcat, 64, h4);
    k_prop1w<<<nf, 256, 0, stream>>>(h4, row_ptr, col, dinv, b3, xcat);

    k_head<<<N_GRAPHS, 128, 0, stream>>>(xcat, c1w, c1b, c2w, c2b,
                                         l1w, l1b, l2w, l2b, out);
}

// Round 17
// 444.373 us; speedup vs baseline: 2.5730x; 1.0256x over previous
//
#include <hip/hip_runtime.h>
#include <hip/hip_bf16.h>
#include <math.h>

#define N_NODES 100000
#define N_EDGES 3200000
#define HID 32
#define K_TOP 30
#define N_GRAPHS 2000
#define NPG 50
#define TLD 97
#define DENSE 352

#define NB 256            // dst-range buckets
#define NPB 391           // nodes per bucket
#define CAP 14336         // bucket capacity (mean 12512, +16 sigma)
#define NBLK 512
#define CE  ((N_EDGES + NBLK - 1) / NBLK)

// ---------------- CSR build: packed bucket partition (unchanged) ----------------
__global__ __launch_bounds__(256) void k_bucket(const int* __restrict__ dst,
                                                const int* __restrict__ src,
                                                int* __restrict__ gcount,
                                                int* __restrict__ buf) {
    __shared__ int hist[NB];
    __shared__ int base_l[NB];
    int tid = threadIdx.x;
    int e0 = blockIdx.x * CE;
    int e1 = e0 + CE; if (e1 > N_EDGES) e1 = N_EDGES;
    hist[tid] = 0;
    __syncthreads();
    for (int e = e0 + tid; e < e1; e += 256) {
        int d = dst[e];
        atomicAdd(&hist[d / NPB], 1);
    }
    __syncthreads();
    int cnt = hist[tid];
    base_l[tid] = cnt ? atomicAdd(&gcount[tid], cnt) : 0;
    __syncthreads();
    hist[tid] = 0;
    __syncthreads();
    for (int e = e0 + tid; e < e1; e += 256) {
        int d = dst[e];
        int s = src[e];
        int b = d / NPB;
        int r = atomicAdd(&hist[b], 1);
        buf[b * CAP + base_l[b] + r] = ((d - b * NPB) << 17) | s;
    }
}

__global__ __launch_bounds__(512) void k_build(const int* __restrict__ buf,
                                               const int* __restrict__ gcount,
                                               int* __restrict__ row_ptr,
                                               float* __restrict__ dinv,
                                               int* __restrict__ col) {
    __shared__ int sb[NB];
    __shared__ int s[512];
    int k = blockIdx.x;
    int tid = threadIdx.x;
    if (tid < NB) sb[tid] = gcount[tid];
    __syncthreads();
    for (int off = 1; off < NB; off <<= 1) {
        int t = (tid < NB && tid >= off) ? sb[tid - off] : 0;
        __syncthreads();
        if (tid < NB) sb[tid] += t;
        __syncthreads();
    }
    int rowbase = (k == 0) ? 0 : sb[k - 1];
    int cnt = gcount[k];
    if (k == NB - 1 && tid == 0) row_ptr[N_NODES] = sb[NB - 1];
    int lo = k * NPB;
    const int* b = buf + k * CAP;
    s[tid] = 0;
    __syncthreads();
    for (int i = tid; i < cnt; i += 512)
        atomicAdd(&s[b[i] >> 17], 1);
    __syncthreads();
    int mydeg = s[tid];
    bool valid = (tid < NPB) && (lo + tid < N_NODES);
    if (valid) dinv[lo + tid] = rsqrtf((float)(mydeg + 1));
    for (int off = 1; off < 512; off <<= 1) {
        int t = (tid >= off) ? s[tid - off] : 0;
        __syncthreads();
        s[tid] += t;
        __syncthreads();
    }
    int excl = s[tid] - mydeg;
    if (valid) row_ptr[lo + tid] = rowbase + excl;
    __syncthreads();
    s[tid] = excl;
    __syncthreads();
    for (int i = tid; i < cnt; i += 512) {
        int v = b[i];
        int r = atomicAdd(&s[v >> 17], 1);
        col[rowbase + r] = v & 0x1FFFF;
    }
}

// ---------------- fused GCN layers ----------------
__global__ void k_embed_lin0(const int* __restrict__ z, const float* __restrict__ zt,
                             const float* __restrict__ W, const float* __restrict__ dinv,
                             float* __restrict__ hs) {
    __shared__ float Ws[32 * 32];
    int tid = threadIdx.x;
    for (int i = tid; i < 1024; i += 256) Ws[i] = W[i];
    __syncthreads();
    int gi = blockIdx.x * 256 + tid;
    if (gi >= N_NODES * 32) return;
    int n = gi >> 5, f = gi & 31;
    float v = zt[z[n] * 32 + f];
    float acc = 0.f;
#pragma unroll
    for (int f2 = 0; f2 < 32; ++f2)
        acc += __shfl(v, f2, 32) * Ws[f2 * 32 + f];
    hs[gi] = acc * dinv[n];
}

// Structure B gather: 8 lanes/node, float4 acc; one dwordx4 instr = 8 rows.
// Edge-order-sequential adds (predicated remainder) -> bit-identical sums.
__device__ __forceinline__ void gather8(const float* __restrict__ hs,
                                        const int* __restrict__ col,
                                        int beg, int end, int j, float4& acc) {
    int deg = end - beg;
    int nch = (deg + 7) >> 3;
    for (int it = 0; it < nch; ++it) {
        int eidx = beg + (it << 3) + j;
        int cj = (eidx < end) ? col[eidx] : 0;
        float4 vals[8];
#pragma unroll
        for (int i = 0; i < 8; ++i) {
            int ci = __shfl(cj, i, 8);
            vals[i] = *(const float4*)&hs[ci * 32 + 4 * j];
        }
        int rem = deg - (it << 3);
        if (rem >= 8) {
#pragma unroll
            for (int i = 0; i < 8; ++i) {
                acc.x += vals[i].x; acc.y += vals[i].y;
                acc.z += vals[i].z; acc.w += vals[i].w;
            }
        } else {
#pragma unroll
            for (int i = 0; i < 8; ++i)
                if (i < rem) {
                    acc.x += vals[i].x; acc.y += vals[i].y;
                    acc.z += vals[i].z; acc.w += vals[i].w;
                }
        }
    }
}

// one GCN layer: gather-normalize-tanh, xcat column block, fused next linear.
// 256 thr = 32 nodes/block; grid 3125 (exact).
__global__ __launch_bounds__(256) void k_layer(const float* __restrict__ hs,
                        const int* __restrict__ row_ptr,
                        const int* __restrict__ col, const float* __restrict__ dinv,
                        const float* __restrict__ b, const float* __restrict__ Wnext,
                        float* __restrict__ xcat, int coloff,
                        float* __restrict__ hs_out) {
    __shared__ float4 Ws[32][8];   // Ws[f][j] = W[f][4j..4j+3]
    int tid = threadIdx.x;
    {
        int f = tid >> 3, j = tid & 7;
        Ws[f][j] = make_float4(Wnext[f * 32 + 4 * j], Wnext[f * 32 + 4 * j + 1],
                               Wnext[f * 32 + 4 * j + 2], Wnext[f * 32 + 4 * j + 3]);
    }
    __syncthreads();
    int n = blockIdx.x * 32 + (tid >> 3);
    int j = tid & 7;
    float dn = dinv[n];
    int beg = row_ptr[n], end = row_ptr[n + 1];
    float4 acc = *(const float4*)&hs[n * 32 + 4 * j];
    gather8(hs, col, beg, end, j, acc);
    float4 vv;
    vv.x = tanhf(acc.x * dn + b[4 * j + 0]);
    vv.y = tanhf(acc.y * dn + b[4 * j + 1]);
    vv.z = tanhf(acc.z * dn + b[4 * j + 2]);
    vv.w = tanhf(acc.w * dn + b[4 * j + 3]);
    xcat[n * 97 + coloff + 4 * j + 0] = vv.x;
    xcat[n * 97 + coloff + 4 * j + 1] = vv.y;
    xcat[n * 97 + coloff + 4 * j + 2] = vv.z;
    xcat[n * 97 + coloff + 4 * j + 3] = vv.w;
    float4 o = make_float4(0.f, 0.f, 0.f, 0.f);
#pragma unroll
    for (int jj = 0; jj < 8; ++jj) {
        float vx = __shfl(vv.x, jj, 8);
        float vy = __shfl(vv.y, jj, 8);
        float vz = __shfl(vv.z, jj, 8);
        float vw = __shfl(vv.w, jj, 8);
        float4 w0 = Ws[4 * jj + 0][j];
        float4 w1 = Ws[4 * jj + 1][j];
        float4 w2 = Ws[4 * jj + 2][j];
        float4 w3 = Ws[4 * jj + 3][j];
        o.x += vx * w0.x; o.x += vy * w1.x; o.x += vz * w2.x; o.x += vw * w3.x;
        o.y += vx * w0.y; o.y += vy * w1.y; o.y += vz * w2.y; o.y += vw * w3.y;
        o.z += vx * w0.z; o.z += vy * w1.z; o.z += vz * w2.z; o.z += vw * w3.z;
        o.w += vx * w0.w; o.w += vy * w1.w; o.w += vz * w2.w; o.w += vw * w3.w;
    }
    *(float4*)&hs_out[n * 32 + 4 * j] =
        make_float4(o.x * dn, o.y * dn, o.z * dn, o.w * dn);
}

__global__ __launch_bounds__(256) void k_layer_last(const float* __restrict__ hs,
                             const int* __restrict__ row_ptr,
                             const int* __restrict__ col, const float* __restrict__ dinv,
                             const float* __restrict__ b, const float* __restrict__ W3,
                             float* __restrict__ xcat, int coloff,
                             float* __restrict__ h4) {
    int tid = threadIdx.x;
    int n = blockIdx.x * 32 + (tid >> 3);
    int j = tid & 7;
    float dn = dinv[n];
    int beg = row_ptr[n], end = row_ptr[n + 1];
    float4 acc = *(const float4*)&hs[n * 32 + 4 * j];
    gather8(hs, col, beg, end, j, acc);
    float4 vv;
    vv.x = tanhf(acc.x * dn + b[4 * j + 0]);
    vv.y = tanhf(acc.y * dn + b[4 * j + 1]);
    vv.z = tanhf(acc.z * dn + b[4 * j + 2]);
    vv.w = tanhf(acc.w * dn + b[4 * j + 3]);
    xcat[n * 97 + coloff + 4 * j + 0] = vv.x;
    xcat[n * 97 + coloff + 4 * j + 1] = vv.y;
    xcat[n * 97 + coloff + 4 * j + 2] = vv.z;
    xcat[n * 97 + coloff + 4 * j + 3] = vv.w;
    float p = vv.x * W3[4 * j + 0];
    p += vv.y * W3[4 * j + 1];
    p += vv.z * W3[4 * j + 2];
    p += vv.w * W3[4 * j + 3];
    p += __shfl_xor(p, 1, 8);
    p += __shfl_xor(p, 2, 8);
    p += __shfl_xor(p, 4, 8);
    if (j == 0) h4[n] = p * dn;
}

// wave-cooperative final propagation (unchanged)
__global__ void k_prop1w(const float* __restrict__ hs4, const int* __restrict__ row_ptr,
                         const int* __restrict__ col, const float* __restrict__ dinv,
                         const float* __restrict__ b3, float* __restrict__ xcat) {
    int gi = blockIdx.x * 256 + threadIdx.x;
    if (gi >= N_NODES * 32) return;
    int n = gi >> 5, lane = gi & 31;
    int beg = row_ptr[n], end = row_ptr[n + 1];
    float part = 0.f;
    for (int e = beg + lane; e < end; e += 32)
        part += hs4[col[e]];
#pragma unroll
    for (int off = 16; off >= 1; off >>= 1) part += __shfl_xor(part, off);
    if (lane == 0) {
        float acc = hs4[n] + part;
        xcat[n * 97 + 96] = tanhf(acc * dinv[n] + b3[0]);
    }
}

// ---------------- fused sort-pool + CNN + MLP head (unchanged) ----------------
__global__ __launch_bounds__(128) void k_head(
    const float* __restrict__ xcat,
    const float* __restrict__ w1, const float* __restrict__ b1,
    const float* __restrict__ w2, const float* __restrict__ b2,
    const float* __restrict__ l1w, const float* __restrict__ l1b,
    const float* __restrict__ l2w, const float* __restrict__ l2b,
    float* __restrict__ out) {
    __shared__ float xk[K_TOP][97];
    __shared__ float w1s[16 * 97];
    __shared__ float w2s[32 * 80];
    __shared__ float y1[16][K_TOP];
    __shared__ float y1p[16][15];
    __shared__ float y2[DENSE];
    __shared__ float z1[128];
    __shared__ int   sel[K_TOP];
    __shared__ float red[2];

    int g = blockIdx.x;
    int tid = threadIdx.x;
    int base = g * NPG;

    for (int i = tid; i < 16 * 97; i += 128) w1s[i] = w1[i];
    for (int i = tid; i < 32 * 80; i += 128) w2s[i] = w2[i];

    if (tid < 64) {
        float v; int idx;
        if (tid < NPG) { v = xcat[(base + tid) * 97 + 96]; idx = tid; }
        else           { v = -INFINITY;                    idx = 64 + tid; }
        for (int k = 2; k <= 64; k <<= 1) {
            for (int j = k >> 1; j > 0; j >>= 1) {
                float ov = __shfl_xor(v, j);
                int   oi = __shfl_xor(idx, j);
                bool lower = (tid & j) == 0;
                bool dirA  = (tid & k) == 0;
                bool mineFirst = (v > ov) || (v == ov && idx < oi);
                bool keep = lower ? (mineFirst == dirA) : (mineFirst != dirA);
                if (!keep) { v = ov; idx = oi; }
            }
        }
        if (tid < K_TOP) sel[tid] = idx;
    }
    __syncthreads();

    for (int i = tid; i < K_TOP * 97; i += 128) {
        int j = i / 97, d = i - j * 97;
        xk[j][d] = xcat[(base + sel[j]) * 97 + d];
    }
    __syncthreads();

    for (int i = tid; i < 16 * K_TOP; i += 128) {
        int c = i / K_TOP, j = i - c * K_TOP;
        float acc = b1[c];
#pragma unroll
        for (int d = 0; d < 97; ++d) acc += xk[j][d] * w1s[c * 97 + d];
        y1[c][j] = fmaxf(acc, 0.f);
    }
    __syncthreads();

    for (int i = tid; i < 16 * 15; i += 128) {
        int c = i / 15, p = i - c * 15;
        y1p[c][p] = fmaxf(y1[c][2 * p], y1[c][2 * p + 1]);
    }
    __syncthreads();

    for (int i = tid; i < 32 * 11; i += 128) {
        int o = i / 11, p = i - o * 11;
        float acc = b2[o];
#pragma unroll
        for (int ci = 0; ci < 16; ++ci)
#pragma unroll
            for (int t = 0; t < 5; ++t)
                acc += y1p[ci][p + t] * w2s[o * 80 + ci * 5 + t];
        y2[o * 11 + p] = fmaxf(acc, 0.f);
    }
    __syncthreads();

    {
        float acc = l1b[tid];
        for (int r = 0; r < DENSE; ++r) acc += y2[r] * l1w[r * 128 + tid];
        z1[tid] = fmaxf(acc, 0.f);
    }
    __syncthreads();

    float p = z1[tid] * l2w[tid];
    for (int off = 32; off >= 1; off >>= 1) p += __shfl_xor(p, off);
    if ((tid & 63) == 0) red[tid >> 6] = p;
    __syncthreads();
    if (tid == 0) out[g] = red[0] + red[1] + l2b[0];
}

extern "C" void kernel_launch(void* const* d_in, const int* in_sizes, int n_in,
                              void* d_out, int out_size, void* d_ws, size_t ws_size,
                              hipStream_t stream) {
    const int*   z   = (const int*)d_in[0];
    const int*   ei  = (const int*)d_in[1];
    const float* zt  = (const float*)d_in[3];
    const float* W0  = (const float*)d_in[4];  const float* b0  = (const float*)d_in[5];
    const float* W1  = (const float*)d_in[6];  const float* b1g = (const float*)d_in[7];
    const float* W2  = (const float*)d_in[8];  const float* b2g = (const float*)d_in[9];
    const float* W3  = (const float*)d_in[10]; const float* b3  = (const float*)d_in[11];
    const float* c1w = (const float*)d_in[12]; const float* c1b = (const float*)d_in[13];
    const float* c2w = (const float*)d_in[14]; const float* c2b = (const float*)d_in[15];
    const float* l1w = (const float*)d_in[16]; const float* l1b = (const float*)d_in[17];
    const float* l2w = (const float*)d_in[18]; const float* l2b = (const float*)d_in[19];
    float* out = (float*)d_out;

    char* ws = (char*)d_ws;
    size_t off = 0;
    auto alloc = [&](size_t bytes) {
        void* p = ws + off;
        off += (bytes + 255) & ~(size_t)255;
        return p;
    };
    int*   row_ptr   = (int*)alloc((size_t)(N_NODES + 1) * 4);
    float* dinv      = (float*)alloc((size_t)N_NODES * 4);
    int*   col       = (int*)alloc((size_t)N_EDGES * 4);
    int*   gcount    = (int*)alloc((size_t)NB * 4);
    int*   bucketbuf = (int*)alloc((size_t)NB * CAP * 4);
    float* hA        = (float*)alloc((size_t)N_NODES * 32 * 4);
    float* hB        = (float*)alloc((size_t)N_NODES * 32 * 4);
    float* h4        = (float*)alloc((size_t)N_NODES * 4);
    float* xcat      = (float*)alloc((size_t)N_NODES * 97 * 4);

    const int* srcp = ei;
    const int* dstp = ei + N_EDGES;

    hipMemsetAsync(gcount, 0, (size_t)NB * 4, stream);

    int nf = (N_NODES * 32 + 255) / 256;   // 12500
    int nl = N_NODES / 32;                 // 3125 (exact)

    k_bucket<<<NBLK, 256, 0, stream>>>(dstp, srcp, gcount, bucketbuf);
    k_build<<<NB, 512, 0, stream>>>(bucketbuf, gcount, row_ptr, dinv, col);

    k_embed_lin0<<<nf, 256, 0, stream>>>(z, zt, W0, dinv, hA);
    k_layer<<<nl, 256, 0, stream>>>(hA, row_ptr, col, dinv, b0, W1, xcat, 0, hB);
    k_layer<<<nl, 256, 0, stream>>>(hB, row_ptr, col, dinv, b1g, W2, xcat, 32, hA);
    k_layer_last<<<nl, 256, 0, stream>>>(hA, row_ptr, col, dinv, b2g, W3, xcat, 64, h4);
    k_prop1w<<<nf, 256, 0, stream>>>(h4, row_ptr, col, dinv, b3, xcat);

    k_head<<<N_GRAPHS, 128, 0, stream>>>(xcat, c1w, c1b, c2w, c2b,
                                         l1w, l1b, l2w, l2b, out);
}